// Round 4
// baseline (398.425 us; speedup 1.0000x reference)
//
#include <hip/hip_runtime.h>
#include <hip/hip_bf16.h>

typedef unsigned short u16;
typedef unsigned int u32;
typedef __attribute__((ext_vector_type(8))) short bf16x8;
typedef __attribute__((ext_vector_type(4))) float f32x4;
typedef __attribute__((ext_vector_type(4))) int   i32x4;
typedef __attribute__((ext_vector_type(4))) float fvec4;

__device__ inline u16 f2bf(float f) {
    union { float f; unsigned u; } v; v.f = f;
    unsigned r = v.u + 0x7fffu + ((v.u >> 16) & 1u);
    return (u16)(r >> 16);
}

__device__ inline f32x4 mfma16(bf16x8 a, bf16x8 b, f32x4 c) {
    return __builtin_amdgcn_mfma_f32_16x16x32_bf16(a, b, c, 0, 0, 0);
}

// async global->LDS, 16B per lane. lds ptr must be wave-uniform; HW adds lane*16.
__device__ inline void gload16(const void* g, void* l) {
    __builtin_amdgcn_global_load_lds(
        (const __attribute__((address_space(1))) unsigned int*)g,
        (__attribute__((address_space(3))) unsigned int*)l, 16, 0, 0);
}

// ---------------------------------------------------------------------------
// Transpose + cast: in[K][N] fp32 -> out[N][K] bf16  (weights)
// ---------------------------------------------------------------------------
__global__ __launch_bounds__(256)
void transpose_cast(const float* __restrict__ in, u16* __restrict__ out, int K, int N) {
    __shared__ float tile[32][33];
    const int n0 = blockIdx.x * 32, k0 = blockIdx.y * 32;
    const int x = threadIdx.x & 31, y = threadIdx.x >> 5;
    for (int i = 0; i < 4; ++i)
        tile[y + i * 8][x] = in[(size_t)(k0 + y + i * 8) * N + n0 + x];
    __syncthreads();
    for (int i = 0; i < 4; ++i) {
        int r = y + i * 8;
        out[(size_t)(n0 + r) * K + k0 + x] = f2bf(tile[x][r]);
    }
}

// ---------------------------------------------------------------------------
// V transpose (bf16): qkv[4096][3072] (V = cols 2048..3071) -> vT[1024][4096]
// ---------------------------------------------------------------------------
__global__ __launch_bounds__(256)
void vtrans(const u16* __restrict__ qkv, u16* __restrict__ vT) {
    __shared__ u32 tl[64][33];
    const int t0 = blockIdx.x * 64, f0 = blockIdx.y * 64;
    const int a = threadIdx.x & 31, yy = threadIdx.x >> 5;
    for (int i = 0; i < 8; ++i) {
        int t = yy + i * 8;
        tl[t][a] = *(const u32*)(qkv + (size_t)(t0 + t) * 3072 + 2048 + f0 + a * 2);
    }
    __syncthreads();
    for (int i = 0; i < 8; ++i) {
        int f = yy + i * 8;
        u32 lo = tl[2 * a][f >> 1], hi = tl[2 * a + 1][f >> 1];
        u32 r = (f & 1) ? ((lo >> 16) | (hi & 0xffff0000u))
                        : ((lo & 0xffffu) | (hi << 16));
        *(u32*)(vT + (size_t)(f0 + f) * 4096 + t0 + 2 * a) = r;
    }
}

// ---------------------------------------------------------------------------
// LayerNorm: x[rows][1024] fp32 -> out bf16. One block (256 thr) per row.
// ---------------------------------------------------------------------------
__global__ __launch_bounds__(256)
void ln_kernel(const float* __restrict__ x, const float* __restrict__ g,
               const float* __restrict__ bvec, u16* __restrict__ out) {
    __shared__ float red[2][4];
    const int row = blockIdx.x, tid = threadIdx.x;
    const float* xr = x + (size_t)row * 1024;
    fvec4 v = *(const fvec4*)(xr + tid * 4);
    float s  = v[0] + v[1] + v[2] + v[3];
    float s2 = v[0]*v[0] + v[1]*v[1] + v[2]*v[2] + v[3]*v[3];
    for (int off = 1; off < 64; off <<= 1) {
        s  += __shfl_xor(s,  off);
        s2 += __shfl_xor(s2, off);
    }
    const int w = tid >> 6;
    if ((tid & 63) == 0) { red[0][w] = s; red[1][w] = s2; }
    __syncthreads();
    s  = red[0][0] + red[0][1] + red[0][2] + red[0][3];
    s2 = red[1][0] + red[1][1] + red[1][2] + red[1][3];
    const float mu  = s * (1.0f / 1024.0f);
    const float var = s2 * (1.0f / 1024.0f) - mu * mu;
    const float rstd = rsqrtf(var + 1e-5f);
    fvec4 gv = *(const fvec4*)(g + tid * 4);
    fvec4 bv = *(const fvec4*)(bvec + tid * 4);
    u16 o4[4];
    for (int i = 0; i < 4; ++i)
        o4[i] = f2bf((v[i] - mu) * rstd * gv[i] + bv[i]);
    u32 lo = (u32)o4[0] | ((u32)o4[1] << 16);
    u32 hi = (u32)o4[2] | ((u32)o4[3] << 16);
    u32* dst = (u32*)(out + (size_t)row * 1024 + tid * 4);
    dst[0] = lo; dst[1] = hi;
}

// ---------------------------------------------------------------------------
// GEMM, double-buffered LDS: C[M][N] = A[M][K] @ Bt[N][K]^T, both bf16.
// Block tile TM x TN, BK=32, 4 waves. global_load_lds for chunk k+1 issued
// right after the barrier, compute on chunk k -> load latency hidden by the
// MFMA phase; ONE barrier per K-iteration.
// MODE 0: out bf16 = acc
// MODE 1: out fp32 = acc + bias[n] + res[m][n]
// MODE 2: out bf16 = gelu(acc + bias[n])   (exact erf)
// ---------------------------------------------------------------------------
template <int MODE, int WM, int WN, int MT, int NT>
__global__ __launch_bounds__(256)
void gemm_db(const u16* __restrict__ A, const u16* __restrict__ Bt,
             const float* __restrict__ bias, const float* __restrict__ res,
             void* __restrict__ out, int M, int N, int K) {
    constexpr int TM = WM * MT * 16;
    constexpr int TN = WN * NT * 16;
    constexpr int AJ = TM / 64;
    constexpr int BJ = TN / 64;
    __shared__ __attribute__((aligned(16))) u16 sA[2][TM * 32];
    __shared__ __attribute__((aligned(16))) u16 sB[2][TN * 32];
    const int tid = threadIdx.x;
    const int lane = tid & 63, w = tid >> 6;
    const int wm = w / WN, wn = w % WN;
    const int q = lane >> 4, l16 = lane & 15;

    f32x4 acc[MT][NT];
#pragma unroll
    for (int i = 0; i < MT; ++i)
#pragma unroll
        for (int j = 0; j < NT; ++j) acc[i][j] = (f32x4)0.0f;

    const int sr = lane >> 2;
    const int kc = (lane & 3) * 8;
    const u16* gA[AJ];
    const u16* gB[BJ];
#pragma unroll
    for (int j = 0; j < AJ; ++j)
        gA[j] = A + (size_t)(blockIdx.x * TM + j * 64 + w * 16 + sr) * K + kc;
#pragma unroll
    for (int j = 0; j < BJ; ++j)
        gB[j] = Bt + (size_t)(blockIdx.y * TN + j * 64 + w * 16 + sr) * K + kc;

    // prologue: stage chunk 0 into buffer 0
#pragma unroll
    for (int j = 0; j < AJ; ++j) gload16(gA[j], &sA[0][(j * 4 + w) * 512]);
#pragma unroll
    for (int j = 0; j < BJ; ++j) gload16(gB[j], &sB[0][(j * 4 + w) * 512]);

    int buf = 0;
    for (int k0 = 0; k0 < K; k0 += 32, buf ^= 1) {
        __syncthreads();   // drains: chunk-k loads (in flight since last iter) + prev ds_reads
        if (k0 + 32 < K) {
#pragma unroll
            for (int j = 0; j < AJ; ++j)
                gload16(gA[j] + k0 + 32, &sA[buf ^ 1][(j * 4 + w) * 512]);
#pragma unroll
            for (int j = 0; j < BJ; ++j)
                gload16(gB[j] + k0 + 32, &sB[buf ^ 1][(j * 4 + w) * 512]);
        }
        bf16x8 af[MT], bf[NT];
#pragma unroll
        for (int mt = 0; mt < MT; ++mt)
            af[mt] = *(const bf16x8*)&sA[buf][(wm * MT * 16 + mt * 16 + l16) * 32 + q * 8];
#pragma unroll
        for (int nt = 0; nt < NT; ++nt)
            bf[nt] = *(const bf16x8*)&sB[buf][(wn * NT * 16 + nt * 16 + l16) * 32 + q * 8];
#pragma unroll
        for (int mt = 0; mt < MT; ++mt)
#pragma unroll
            for (int nt = 0; nt < NT; ++nt)
                acc[mt][nt] = mfma16(af[mt], bf[nt], acc[mt][nt]);
    }

#pragma unroll
    for (int mt = 0; mt < MT; ++mt)
#pragma unroll
        for (int nt = 0; nt < NT; ++nt)
#pragma unroll
            for (int r = 0; r < 4; ++r) {
                const int row = blockIdx.x * TM + wm * MT * 16 + mt * 16 + q * 4 + r;
                const int col = blockIdx.y * TN + wn * NT * 16 + nt * 16 + l16;
                const size_t idx = (size_t)row * N + col;
                float v = acc[mt][nt][r];
                if (MODE == 0) {
                    ((u16*)out)[idx] = f2bf(v);
                } else if (MODE == 1) {
                    ((float*)out)[idx] = v + bias[col] + res[idx];
                } else {
                    float t = v + bias[col];
                    ((u16*)out)[idx] = f2bf(t * 0.5f * (1.0f + erff(t * 0.70710678118f)));
                }
            }
}

// ---------------------------------------------------------------------------
// Flash attention v3 (unchanged from round 3).
// ---------------------------------------------------------------------------
__global__ __launch_bounds__(256)
void attention3(const u16* __restrict__ qkv, const u16* __restrict__ vT,
                u16* __restrict__ o) {
    __shared__ __attribute__((aligned(16))) u16 sK[64][72];   // [key][d]
    __shared__ __attribute__((aligned(16))) u16 sV[64][72];   // [d][key]

    const int tid = threadIdx.x;
    const int lane = tid & 63, w = tid >> 6;
    const int qc = lane >> 4, l16 = lane & 15;
    const int bx = blockIdx.x;
    const int qt = bx & 15, h = (bx >> 4) & 15, b = bx >> 8;
    const int rowbase = qt * 128 + w * 32;

    bf16x8 aQ[2][2];
#pragma unroll
    for (int mtq = 0; mtq < 2; ++mtq)
#pragma unroll
        for (int kd = 0; kd < 2; ++kd)
            aQ[mtq][kd] = *(const bf16x8*)(qkv +
                (size_t)(b * 2048 + rowbase + mtq * 16 + l16) * 3072 +
                h * 64 + kd * 32 + qc * 8);

    f32x4 accO[2][4];
#pragma unroll
    for (int mtq = 0; mtq < 2; ++mtq)
#pragma unroll
        for (int dt = 0; dt < 4; ++dt) accO[mtq][dt] = (f32x4)0.0f;
    float lsum[2] = {0.0f, 0.0f};

    const int srr = tid >> 3;            // 0..31
    const int sc8 = (tid & 7) * 8;       // 0..56
    const u16* gK = qkv + (size_t)(b * 2048 + srr) * 3072 + 1024 + h * 64 + sc8;
    const u16* gV = vT + (size_t)(h * 64 + srr) * 4096 + b * 2048 + sc8;

    i32x4 cK[2], cV[2];
    cK[0] = *(const i32x4*)gK;
    cK[1] = *(const i32x4*)(gK + (size_t)32 * 3072);
    cV[0] = *(const i32x4*)gV;
    cV[1] = *(const i32x4*)(gV + (size_t)32 * 4096);

    const int sig_base = ((l16 >> 2) << 3) + (l16 & 3);   // q*8 + r

    for (int kc = 0; kc < 32; ++kc) {
        __syncthreads();
        *(i32x4*)&sK[srr][sc8]      = cK[0];
        *(i32x4*)&sK[srr + 32][sc8] = cK[1];
        *(i32x4*)&sV[srr][sc8]      = cV[0];
        *(i32x4*)&sV[srr + 32][sc8] = cV[1];
        const int kn = (kc + 1 < 32) ? kc + 1 : 31;
        i32x4 nK[2], nV[2];
        nK[0] = *(const i32x4*)(gK + (size_t)kn * 64 * 3072);
        nK[1] = *(const i32x4*)(gK + ((size_t)kn * 64 + 32) * 3072);
        nV[0] = *(const i32x4*)(gV + kn * 64);
        nV[1] = *(const i32x4*)(gV + (size_t)32 * 4096 + kn * 64);
        __syncthreads();

        bf16x8 kf[4][2];
#pragma unroll
        for (int mk = 0; mk < 4; ++mk) {
            const int krow = ((mk & 1) << 5) + ((mk >> 1) << 2) + sig_base;
            kf[mk][0] = *(const bf16x8*)&sK[krow][qc * 8];
            kf[mk][1] = *(const bf16x8*)&sK[krow][32 + qc * 8];
        }

        f32x4 s[2][4];
#pragma unroll
        for (int mtq = 0; mtq < 2; ++mtq)
#pragma unroll
            for (int mk = 0; mk < 4; ++mk) {
                f32x4 z = (f32x4)0.0f;
                z = mfma16(kf[mk][0], aQ[mtq][0], z);
                z = mfma16(kf[mk][1], aQ[mtq][1], z);
                s[mtq][mk] = z;
            }

        bf16x8 pf[2][2];
#pragma unroll
        for (int mtq = 0; mtq < 2; ++mtq) {
            float ls = 0.0f;
#pragma unroll
            for (int mk = 0; mk < 4; ++mk)
#pragma unroll
                for (int r = 0; r < 4; ++r) {
                    float p = __expf(s[mtq][mk][r] * 0.125f);
                    s[mtq][mk][r] = p;
                    ls += p;
                }
            lsum[mtq] += ls;
#pragma unroll
            for (int kt = 0; kt < 2; ++kt)
#pragma unroll
                for (int j = 0; j < 4; ++j) {
                    pf[mtq][kt][j]     = (short)f2bf(s[mtq][kt][j]);
                    pf[mtq][kt][4 + j] = (short)f2bf(s[mtq][2 + kt][j]);
                }
        }

#pragma unroll
        for (int kt = 0; kt < 2; ++kt)
#pragma unroll
            for (int dt = 0; dt < 4; ++dt) {
                bf16x8 vf = *(const bf16x8*)&sV[dt * 16 + l16][kt * 32 + qc * 8];
#pragma unroll
                for (int mtq = 0; mtq < 2; ++mtq)
                    accO[mtq][dt] = mfma16(pf[mtq][kt], vf, accO[mtq][dt]);
            }

        cK[0] = nK[0]; cK[1] = nK[1];
        cV[0] = nV[0]; cV[1] = nV[1];
    }

#pragma unroll
    for (int mtq = 0; mtq < 2; ++mtq) {
        lsum[mtq] += __shfl_xor(lsum[mtq], 16);
        lsum[mtq] += __shfl_xor(lsum[mtq], 32);
    }

#pragma unroll
    for (int mtq = 0; mtq < 2; ++mtq)
#pragma unroll
        for (int r = 0; r < 4; ++r) {
            const float lr = __shfl(lsum[mtq], qc * 4 + r, 16);
            const float inv = 1.0f / lr;
            const size_t tok = (size_t)b * 2048 + rowbase + mtq * 16 + qc * 4 + r;
#pragma unroll
            for (int dt = 0; dt < 4; ++dt)
                o[tok * 1024 + h * 64 + dt * 16 + l16] = f2bf(accO[mtq][dt][r] * inv);
        }
}

// ---------------------------------------------------------------------------
extern "C" void kernel_launch(void* const* d_in, const int* in_sizes, int n_in,
                              void* d_out, int out_size, void* d_ws, size_t ws_size,
                              hipStream_t stream) {
    const float* x      = (const float*)d_in[0];
    const float* ln1_g  = (const float*)d_in[1];
    const float* ln1_b  = (const float*)d_in[2];
    const float* w_qkv  = (const float*)d_in[3];
    const float* w_proj = (const float*)d_in[4];
    const float* b_proj = (const float*)d_in[5];
    const float* ln2_g  = (const float*)d_in[6];
    const float* ln2_b  = (const float*)d_in[7];
    const float* w_fc1  = (const float*)d_in[8];
    const float* b_fc1  = (const float*)d_in[9];
    const float* w_fc2  = (const float*)d_in[10];
    const float* b_fc2  = (const float*)d_in[11];
    float* out = (float*)d_out;

    // workspace layout (bytes); total ~104 MB
    char* ws = (char*)d_ws;
    u16*   wqkvT  = (u16*)(ws + 0);           //  6 MB  [3072][1024]
    u16*   wprojT = (u16*)(ws + 6291456);     //  2 MB  [1024][1024]
    u16*   wfc1T  = (u16*)(ws + 8388608);     //  8 MB  [4096][1024]
    u16*   wfc2T  = (u16*)(ws + 16777216);    //  8 MB  [1024][4096]
    u16*   hA     = (u16*)(ws + 25165824);    //  8 MB  ln1 out; reused for attn out
    u16*   qkv    = (u16*)(ws + 33554432);    // 24 MB  [4096][3072]; reused for h2
    float* x1     = (float*)(ws + 58720256);  // 16 MB  [4096][1024] fp32
    u16*   gbuf   = (u16*)(ws + 75497472);    // 32 MB  [4096][4096] gelu out
    u16*   vT     = (u16*)(ws + 75497472);    //  8 MB  aliases gbuf (dead before fc1)

    dim3 blk(256);
    transpose_cast<<<dim3(96, 32),  blk, 0, stream>>>(w_qkv,  wqkvT, 1024, 3072);
    transpose_cast<<<dim3(32, 32),  blk, 0, stream>>>(w_proj, wprojT, 1024, 1024);
    transpose_cast<<<dim3(128, 32), blk, 0, stream>>>(w_fc1,  wfc1T, 1024, 4096);
    transpose_cast<<<dim3(32, 128), blk, 0, stream>>>(w_fc2,  wfc2T, 4096, 1024);

    ln_kernel<<<4096, blk, 0, stream>>>(x, ln1_g, ln1_b, hA);
    gemm_db<0, 2, 2, 4, 4><<<dim3(32, 24), blk, 0, stream>>>(hA, wqkvT, nullptr, nullptr, qkv, 4096, 3072, 1024);
    vtrans<<<dim3(64, 16), blk, 0, stream>>>(qkv, vT);
    attention3<<<512, blk, 0, stream>>>(qkv, vT, hA);
    gemm_db<1, 2, 2, 4, 4><<<dim3(32, 8), blk, 0, stream>>>(hA, wprojT, b_proj, x, x1, 4096, 1024, 1024);

    u16* h2 = qkv;  // qkv dead after attention
    ln_kernel<<<4096, blk, 0, stream>>>(x1, ln2_g, ln2_b, h2);
    gemm_db<2, 2, 2, 4, 4><<<dim3(32, 32), blk, 0, stream>>>(h2, wfc1T, b_fc1, nullptr, gbuf, 4096, 4096, 1024);
    gemm_db<1, 2, 2, 4, 4><<<dim3(32, 8), blk, 0, stream>>>(gbuf, wfc2T, b_fc2, x1, out, 4096, 1024, 4096);
}

// Round 5
// 383.765 us; speedup vs baseline: 1.0382x; 1.0382x over previous
//
#include <hip/hip_runtime.h>
#include <hip/hip_bf16.h>

typedef unsigned short u16;
typedef unsigned int u32;
typedef __attribute__((ext_vector_type(8))) short bf16x8;
typedef __attribute__((ext_vector_type(4))) float f32x4;
typedef __attribute__((ext_vector_type(4))) int   i32x4;
typedef __attribute__((ext_vector_type(4))) float fvec4;

__device__ inline u16 f2bf(float f) {
    union { float f; unsigned u; } v; v.f = f;
    unsigned r = v.u + 0x7fffu + ((v.u >> 16) & 1u);
    return (u16)(r >> 16);
}

__device__ inline f32x4 mfma16(bf16x8 a, bf16x8 b, f32x4 c) {
    return __builtin_amdgcn_mfma_f32_16x16x32_bf16(a, b, c, 0, 0, 0);
}

// async global->LDS, 16B per lane. lds ptr must be wave-uniform; HW adds lane*16.
__device__ inline void gload16(const void* g, void* l) {
    __builtin_amdgcn_global_load_lds(
        (const __attribute__((address_space(1))) unsigned int*)g,
        (__attribute__((address_space(3))) unsigned int*)l, 16, 0, 0);
}

// ---------------------------------------------------------------------------
// Transpose + cast: in[K][N] fp32 -> out[N][K] bf16  (weights)
// ---------------------------------------------------------------------------
__global__ __launch_bounds__(256)
void transpose_cast(const float* __restrict__ in, u16* __restrict__ out, int K, int N) {
    __shared__ float tile[32][33];
    const int n0 = blockIdx.x * 32, k0 = blockIdx.y * 32;
    const int x = threadIdx.x & 31, y = threadIdx.x >> 5;
    for (int i = 0; i < 4; ++i)
        tile[y + i * 8][x] = in[(size_t)(k0 + y + i * 8) * N + n0 + x];
    __syncthreads();
    for (int i = 0; i < 4; ++i) {
        int r = y + i * 8;
        out[(size_t)(n0 + r) * K + k0 + x] = f2bf(tile[x][r]);
    }
}

// ---------------------------------------------------------------------------
// V transpose (bf16): qkv[4096][3072] (V = cols 2048..3071) -> vT[1024][4096]
// ---------------------------------------------------------------------------
__global__ __launch_bounds__(256)
void vtrans(const u16* __restrict__ qkv, u16* __restrict__ vT) {
    __shared__ u32 tl[64][33];
    const int t0 = blockIdx.x * 64, f0 = blockIdx.y * 64;
    const int a = threadIdx.x & 31, yy = threadIdx.x >> 5;
    for (int i = 0; i < 8; ++i) {
        int t = yy + i * 8;
        tl[t][a] = *(const u32*)(qkv + (size_t)(t0 + t) * 3072 + 2048 + f0 + a * 2);
    }
    __syncthreads();
    for (int i = 0; i < 8; ++i) {
        int f = yy + i * 8;
        u32 lo = tl[2 * a][f >> 1], hi = tl[2 * a + 1][f >> 1];
        u32 r = (f & 1) ? ((lo >> 16) | (hi & 0xffff0000u))
                        : ((lo & 0xffffu) | (hi << 16));
        *(u32*)(vT + (size_t)(f0 + f) * 4096 + t0 + 2 * a) = r;
    }
}

// ---------------------------------------------------------------------------
// LayerNorm: x[rows][1024] fp32 -> out bf16. One block (256 thr) per row.
// ---------------------------------------------------------------------------
__global__ __launch_bounds__(256)
void ln_kernel(const float* __restrict__ x, const float* __restrict__ g,
               const float* __restrict__ bvec, u16* __restrict__ out) {
    __shared__ float red[2][4];
    const int row = blockIdx.x, tid = threadIdx.x;
    const float* xr = x + (size_t)row * 1024;
    fvec4 v = *(const fvec4*)(xr + tid * 4);
    float s  = v[0] + v[1] + v[2] + v[3];
    float s2 = v[0]*v[0] + v[1]*v[1] + v[2]*v[2] + v[3]*v[3];
    for (int off = 1; off < 64; off <<= 1) {
        s  += __shfl_xor(s,  off);
        s2 += __shfl_xor(s2, off);
    }
    const int w = tid >> 6;
    if ((tid & 63) == 0) { red[0][w] = s; red[1][w] = s2; }
    __syncthreads();
    s  = red[0][0] + red[0][1] + red[0][2] + red[0][3];
    s2 = red[1][0] + red[1][1] + red[1][2] + red[1][3];
    const float mu  = s * (1.0f / 1024.0f);
    const float var = s2 * (1.0f / 1024.0f) - mu * mu;
    const float rstd = rsqrtf(var + 1e-5f);
    fvec4 gv = *(const fvec4*)(g + tid * 4);
    fvec4 bv = *(const fvec4*)(bvec + tid * 4);
    u16 o4[4];
    for (int i = 0; i < 4; ++i)
        o4[i] = f2bf((v[i] - mu) * rstd * gv[i] + bv[i]);
    u32 lo = (u32)o4[0] | ((u32)o4[1] << 16);
    u32 hi = (u32)o4[2] | ((u32)o4[3] << 16);
    u32* dst = (u32*)(out + (size_t)row * 1024 + tid * 4);
    dst[0] = lo; dst[1] = hi;
}

// ---------------------------------------------------------------------------
// GEMM, BK=64 single-buffered: C[M][N] = A[M][K] @ Bt[N][K]^T, both bf16.
// One LDS stage covers 64 k-columns as two [row][32] panels (kt=0,1); compute
// runs two sub-phases per barrier pair -> half the barriers of BK=32 at the
// same register footprint (frag regs reused across kt).
// MODE 0: out bf16 = acc
// MODE 1: out fp32 = acc + bias[n] + res[m][n]
// MODE 2: out bf16 = gelu(acc + bias[n])   (exact erf)
// ---------------------------------------------------------------------------
template <int MODE, int WM, int WN, int MT, int NT>
__global__ __launch_bounds__(256)
void gemm64(const u16* __restrict__ A, const u16* __restrict__ Bt,
            const float* __restrict__ bias, const float* __restrict__ res,
            void* __restrict__ out, int M, int N, int K) {
    constexpr int TM = WM * MT * 16;
    constexpr int TN = WN * NT * 16;
    constexpr int AJ = TM / 64;     // staging issues per wave per kt
    constexpr int BJ = TN / 64;
    __shared__ __attribute__((aligned(16))) u16 sA[2 * TM * 32];  // [kt][row][32]
    __shared__ __attribute__((aligned(16))) u16 sB[2 * TN * 32];
    const int tid = threadIdx.x;
    const int lane = tid & 63, w = tid >> 6;
    const int wm = w / WN, wn = w % WN;
    const int q = lane >> 4, l16 = lane & 15;

    f32x4 acc[MT][NT];
#pragma unroll
    for (int i = 0; i < MT; ++i)
#pragma unroll
        for (int j = 0; j < NT; ++j) acc[i][j] = (f32x4)0.0f;

    const int sr = lane >> 2;            // 0..15
    const int kc = (lane & 3) * 8;       // 0,8,16,24
    const u16* gA[AJ];
    const u16* gB[BJ];
#pragma unroll
    for (int j = 0; j < AJ; ++j)
        gA[j] = A + (size_t)(blockIdx.x * TM + (j * 4 + w) * 16 + sr) * K + kc;
#pragma unroll
    for (int j = 0; j < BJ; ++j)
        gB[j] = Bt + (size_t)(blockIdx.y * TN + (j * 4 + w) * 16 + sr) * K + kc;

    for (int k0 = 0; k0 < K; k0 += 64) {
#pragma unroll
        for (int kt = 0; kt < 2; ++kt) {
#pragma unroll
            for (int j = 0; j < AJ; ++j)
                gload16(gA[j] + k0 + kt * 32, &sA[kt * TM * 32 + (j * 4 + w) * 512]);
#pragma unroll
            for (int j = 0; j < BJ; ++j)
                gload16(gB[j] + k0 + kt * 32, &sB[kt * TN * 32 + (j * 4 + w) * 512]);
        }
        __syncthreads();
#pragma unroll
        for (int kt = 0; kt < 2; ++kt) {
            bf16x8 af[MT], bf[NT];
#pragma unroll
            for (int mt = 0; mt < MT; ++mt)
                af[mt] = *(const bf16x8*)&sA[kt * TM * 32 +
                         (wm * MT * 16 + mt * 16 + l16) * 32 + q * 8];
#pragma unroll
            for (int nt = 0; nt < NT; ++nt)
                bf[nt] = *(const bf16x8*)&sB[kt * TN * 32 +
                         (wn * NT * 16 + nt * 16 + l16) * 32 + q * 8];
#pragma unroll
            for (int mt = 0; mt < MT; ++mt)
#pragma unroll
                for (int nt = 0; nt < NT; ++nt)
                    acc[mt][nt] = mfma16(af[mt], bf[nt], acc[mt][nt]);
        }
        __syncthreads();
    }

#pragma unroll
    for (int mt = 0; mt < MT; ++mt)
#pragma unroll
        for (int nt = 0; nt < NT; ++nt)
#pragma unroll
            for (int r = 0; r < 4; ++r) {
                const int row = blockIdx.x * TM + wm * MT * 16 + mt * 16 + q * 4 + r;
                const int col = blockIdx.y * TN + wn * NT * 16 + nt * 16 + l16;
                const size_t idx = (size_t)row * N + col;
                float v = acc[mt][nt][r];
                if (MODE == 0) {
                    ((u16*)out)[idx] = f2bf(v);
                } else if (MODE == 1) {
                    ((float*)out)[idx] = v + bias[col] + res[idx];
                } else {
                    float t = v + bias[col];
                    ((u16*)out)[idx] = f2bf(t * 0.5f * (1.0f + erff(t * 0.70710678118f)));
                }
            }
}

// ---------------------------------------------------------------------------
// Flash attention v3 (unchanged from round 3).
// ---------------------------------------------------------------------------
__global__ __launch_bounds__(256)
void attention3(const u16* __restrict__ qkv, const u16* __restrict__ vT,
                u16* __restrict__ o) {
    __shared__ __attribute__((aligned(16))) u16 sK[64][72];   // [key][d]
    __shared__ __attribute__((aligned(16))) u16 sV[64][72];   // [d][key]

    const int tid = threadIdx.x;
    const int lane = tid & 63, w = tid >> 6;
    const int qc = lane >> 4, l16 = lane & 15;
    const int bx = blockIdx.x;
    const int qt = bx & 15, h = (bx >> 4) & 15, b = bx >> 8;
    const int rowbase = qt * 128 + w * 32;

    bf16x8 aQ[2][2];
#pragma unroll
    for (int mtq = 0; mtq < 2; ++mtq)
#pragma unroll
        for (int kd = 0; kd < 2; ++kd)
            aQ[mtq][kd] = *(const bf16x8*)(qkv +
                (size_t)(b * 2048 + rowbase + mtq * 16 + l16) * 3072 +
                h * 64 + kd * 32 + qc * 8);

    f32x4 accO[2][4];
#pragma unroll
    for (int mtq = 0; mtq < 2; ++mtq)
#pragma unroll
        for (int dt = 0; dt < 4; ++dt) accO[mtq][dt] = (f32x4)0.0f;
    float lsum[2] = {0.0f, 0.0f};

    const int srr = tid >> 3;            // 0..31
    const int sc8 = (tid & 7) * 8;       // 0..56
    const u16* gK = qkv + (size_t)(b * 2048 + srr) * 3072 + 1024 + h * 64 + sc8;
    const u16* gV = vT + (size_t)(h * 64 + srr) * 4096 + b * 2048 + sc8;

    i32x4 cK[2], cV[2];
    cK[0] = *(const i32x4*)gK;
    cK[1] = *(const i32x4*)(gK + (size_t)32 * 3072);
    cV[0] = *(const i32x4*)gV;
    cV[1] = *(const i32x4*)(gV + (size_t)32 * 4096);

    const int sig_base = ((l16 >> 2) << 3) + (l16 & 3);   // q*8 + r

    for (int kc = 0; kc < 32; ++kc) {
        __syncthreads();
        *(i32x4*)&sK[srr][sc8]      = cK[0];
        *(i32x4*)&sK[srr + 32][sc8] = cK[1];
        *(i32x4*)&sV[srr][sc8]      = cV[0];
        *(i32x4*)&sV[srr + 32][sc8] = cV[1];
        const int kn = (kc + 1 < 32) ? kc + 1 : 31;
        i32x4 nK[2], nV[2];
        nK[0] = *(const i32x4*)(gK + (size_t)kn * 64 * 3072);
        nK[1] = *(const i32x4*)(gK + ((size_t)kn * 64 + 32) * 3072);
        nV[0] = *(const i32x4*)(gV + kn * 64);
        nV[1] = *(const i32x4*)(gV + (size_t)32 * 4096 + kn * 64);
        __syncthreads();

        bf16x8 kf[4][2];
#pragma unroll
        for (int mk = 0; mk < 4; ++mk) {
            const int krow = ((mk & 1) << 5) + ((mk >> 1) << 2) + sig_base;
            kf[mk][0] = *(const bf16x8*)&sK[krow][qc * 8];
            kf[mk][1] = *(const bf16x8*)&sK[krow][32 + qc * 8];
        }

        f32x4 s[2][4];
#pragma unroll
        for (int mtq = 0; mtq < 2; ++mtq)
#pragma unroll
            for (int mk = 0; mk < 4; ++mk) {
                f32x4 z = (f32x4)0.0f;
                z = mfma16(kf[mk][0], aQ[mtq][0], z);
                z = mfma16(kf[mk][1], aQ[mtq][1], z);
                s[mtq][mk] = z;
            }

        bf16x8 pf[2][2];
#pragma unroll
        for (int mtq = 0; mtq < 2; ++mtq) {
            float ls = 0.0f;
#pragma unroll
            for (int mk = 0; mk < 4; ++mk)
#pragma unroll
                for (int r = 0; r < 4; ++r) {
                    float p = __expf(s[mtq][mk][r] * 0.125f);
                    s[mtq][mk][r] = p;
                    ls += p;
                }
            lsum[mtq] += ls;
#pragma unroll
            for (int kt = 0; kt < 2; ++kt)
#pragma unroll
                for (int j = 0; j < 4; ++j) {
                    pf[mtq][kt][j]     = (short)f2bf(s[mtq][kt][j]);
                    pf[mtq][kt][4 + j] = (short)f2bf(s[mtq][2 + kt][j]);
                }
        }

#pragma unroll
        for (int kt = 0; kt < 2; ++kt)
#pragma unroll
            for (int dt = 0; dt < 4; ++dt) {
                bf16x8 vf = *(const bf16x8*)&sV[dt * 16 + l16][kt * 32 + qc * 8];
#pragma unroll
                for (int mtq = 0; mtq < 2; ++mtq)
                    accO[mtq][dt] = mfma16(pf[mtq][kt], vf, accO[mtq][dt]);
            }

        cK[0] = nK[0]; cK[1] = nK[1];
        cV[0] = nV[0]; cV[1] = nV[1];
    }

#pragma unroll
    for (int mtq = 0; mtq < 2; ++mtq) {
        lsum[mtq] += __shfl_xor(lsum[mtq], 16);
        lsum[mtq] += __shfl_xor(lsum[mtq], 32);
    }

#pragma unroll
    for (int mtq = 0; mtq < 2; ++mtq)
#pragma unroll
        for (int r = 0; r < 4; ++r) {
            const float lr = __shfl(lsum[mtq], qc * 4 + r, 16);
            const float inv = 1.0f / lr;
            const size_t tok = (size_t)b * 2048 + rowbase + mtq * 16 + qc * 4 + r;
#pragma unroll
            for (int dt = 0; dt < 4; ++dt)
                o[tok * 1024 + h * 64 + dt * 16 + l16] = f2bf(accO[mtq][dt][r] * inv);
        }
}

// ---------------------------------------------------------------------------
extern "C" void kernel_launch(void* const* d_in, const int* in_sizes, int n_in,
                              void* d_out, int out_size, void* d_ws, size_t ws_size,
                              hipStream_t stream) {
    const float* x      = (const float*)d_in[0];
    const float* ln1_g  = (const float*)d_in[1];
    const float* ln1_b  = (const float*)d_in[2];
    const float* w_qkv  = (const float*)d_in[3];
    const float* w_proj = (const float*)d_in[4];
    const float* b_proj = (const float*)d_in[5];
    const float* ln2_g  = (const float*)d_in[6];
    const float* ln2_b  = (const float*)d_in[7];
    const float* w_fc1  = (const float*)d_in[8];
    const float* b_fc1  = (const float*)d_in[9];
    const float* w_fc2  = (const float*)d_in[10];
    const float* b_fc2  = (const float*)d_in[11];
    float* out = (float*)d_out;

    // workspace layout (bytes); total ~104 MB
    char* ws = (char*)d_ws;
    u16*   wqkvT  = (u16*)(ws + 0);           //  6 MB  [3072][1024]
    u16*   wprojT = (u16*)(ws + 6291456);     //  2 MB  [1024][1024]
    u16*   wfc1T  = (u16*)(ws + 8388608);     //  8 MB  [4096][1024]
    u16*   wfc2T  = (u16*)(ws + 16777216);    //  8 MB  [1024][4096]
    u16*   hA     = (u16*)(ws + 25165824);    //  8 MB  ln1 out; reused for attn out
    u16*   qkv    = (u16*)(ws + 33554432);    // 24 MB  [4096][3072]; reused for h2
    float* x1     = (float*)(ws + 58720256);  // 16 MB  [4096][1024] fp32
    u16*   gbuf   = (u16*)(ws + 75497472);    // 32 MB  [4096][4096] gelu out
    u16*   vT     = (u16*)(ws + 75497472);    //  8 MB  aliases gbuf (dead before fc1)

    dim3 blk(256);
    transpose_cast<<<dim3(96, 32),  blk, 0, stream>>>(w_qkv,  wqkvT, 1024, 3072);
    transpose_cast<<<dim3(32, 32),  blk, 0, stream>>>(w_proj, wprojT, 1024, 1024);
    transpose_cast<<<dim3(128, 32), blk, 0, stream>>>(w_fc1,  wfc1T, 1024, 4096);
    transpose_cast<<<dim3(32, 128), blk, 0, stream>>>(w_fc2,  wfc2T, 4096, 1024);

    ln_kernel<<<4096, blk, 0, stream>>>(x, ln1_g, ln1_b, hA);
    gemm64<0, 2, 2, 4, 4><<<dim3(32, 24), blk, 0, stream>>>(hA, wqkvT, nullptr, nullptr, qkv, 4096, 3072, 1024);
    vtrans<<<dim3(64, 16), blk, 0, stream>>>(qkv, vT);
    attention3<<<512, blk, 0, stream>>>(qkv, vT, hA);
    gemm64<1, 4, 1, 2, 4><<<dim3(32, 16), blk, 0, stream>>>(hA, wprojT, b_proj, x, x1, 4096, 1024, 1024);

    u16* h2 = qkv;  // qkv dead after attention
    ln_kernel<<<4096, blk, 0, stream>>>(x1, ln2_g, ln2_b, h2);
    gemm64<2, 2, 2, 4, 4><<<dim3(32, 32), blk, 0, stream>>>(h2, wfc1T, b_fc1, nullptr, gbuf, 4096, 4096, 1024);
    gemm64<1, 4, 1, 2, 4><<<dim3(32, 16), blk, 0, stream>>>(gbuf, wfc2T, b_fc2, x1, out, 4096, 1024, 4096);
}

// Round 6
// 369.987 us; speedup vs baseline: 1.0769x; 1.0372x over previous
//
#include <hip/hip_runtime.h>
#include <hip/hip_bf16.h>

typedef unsigned short u16;
typedef unsigned int u32;
typedef __attribute__((ext_vector_type(8))) short bf16x8;
typedef __attribute__((ext_vector_type(4))) float f32x4;
typedef __attribute__((ext_vector_type(4))) int   i32x4;
typedef __attribute__((ext_vector_type(4))) float fvec4;

__device__ inline u16 f2bf(float f) {
    union { float f; unsigned u; } v; v.f = f;
    unsigned r = v.u + 0x7fffu + ((v.u >> 16) & 1u);
    return (u16)(r >> 16);
}

__device__ inline f32x4 mfma16(bf16x8 a, bf16x8 b, f32x4 c) {
    return __builtin_amdgcn_mfma_f32_16x16x32_bf16(a, b, c, 0, 0, 0);
}

// async global->LDS, 16B per lane. lds ptr must be wave-uniform; HW adds lane*16.
__device__ inline void gload16(const void* g, void* l) {
    __builtin_amdgcn_global_load_lds(
        (const __attribute__((address_space(1))) unsigned int*)g,
        (__attribute__((address_space(3))) unsigned int*)l, 16, 0, 0);
}

// ---------------------------------------------------------------------------
// All-weights transpose + cast in ONE launch: 4 segments of 32x32 tiles.
// in[K][N] fp32 -> out[N][K] bf16.
// ---------------------------------------------------------------------------
__global__ __launch_bounds__(256)
void transpose_all(const float* __restrict__ w0, u16* __restrict__ o0,   // qkv  K=1024 N=3072
                   const float* __restrict__ w1, u16* __restrict__ o1,   // proj K=1024 N=1024
                   const float* __restrict__ w2, u16* __restrict__ o2,   // fc1  K=1024 N=4096
                   const float* __restrict__ w3, u16* __restrict__ o3) { // fc2  K=4096 N=1024
    __shared__ float tile[32][33];
    int b = blockIdx.x;
    const float* in; u16* out; int K, N, local;
    if (b < 3072)      { in = w0; out = o0; K = 1024; N = 3072; local = b; }
    else if (b < 4096) { in = w1; out = o1; K = 1024; N = 1024; local = b - 3072; }
    else if (b < 8192) { in = w2; out = o2; K = 1024; N = 4096; local = b - 4096; }
    else               { in = w3; out = o3; K = 4096; N = 1024; local = b - 8192; }
    const int nx = N >> 5;
    const int n0 = (local % nx) * 32, k0 = (local / nx) * 32;
    const int x = threadIdx.x & 31, y = threadIdx.x >> 5;
    for (int i = 0; i < 4; ++i)
        tile[y + i * 8][x] = in[(size_t)(k0 + y + i * 8) * N + n0 + x];
    __syncthreads();
    for (int i = 0; i < 4; ++i) {
        int r = y + i * 8;
        out[(size_t)(n0 + r) * K + k0 + x] = f2bf(tile[x][r]);
    }
}

// ---------------------------------------------------------------------------
// V transpose (bf16): qkv[4096][3072] (V = cols 2048..3071) -> vT[1024][4096]
// ---------------------------------------------------------------------------
__global__ __launch_bounds__(256)
void vtrans(const u16* __restrict__ qkv, u16* __restrict__ vT) {
    __shared__ u32 tl[64][33];
    const int t0 = blockIdx.x * 64, f0 = blockIdx.y * 64;
    const int a = threadIdx.x & 31, yy = threadIdx.x >> 5;
    for (int i = 0; i < 8; ++i) {
        int t = yy + i * 8;
        tl[t][a] = *(const u32*)(qkv + (size_t)(t0 + t) * 3072 + 2048 + f0 + a * 2);
    }
    __syncthreads();
    for (int i = 0; i < 8; ++i) {
        int f = yy + i * 8;
        u32 lo = tl[2 * a][f >> 1], hi = tl[2 * a + 1][f >> 1];
        u32 r = (f & 1) ? ((lo >> 16) | (hi & 0xffff0000u))
                        : ((lo & 0xffffu) | (hi << 16));
        *(u32*)(vT + (size_t)(f0 + f) * 4096 + t0 + 2 * a) = r;
    }
}

// ---------------------------------------------------------------------------
// LayerNorm: x[rows][1024] fp32 -> out bf16. One block (256 thr) per row.
// ---------------------------------------------------------------------------
__global__ __launch_bounds__(256)
void ln_kernel(const float* __restrict__ x, const float* __restrict__ g,
               const float* __restrict__ bvec, u16* __restrict__ out) {
    __shared__ float red[2][4];
    const int row = blockIdx.x, tid = threadIdx.x;
    const float* xr = x + (size_t)row * 1024;
    fvec4 v = *(const fvec4*)(xr + tid * 4);
    float s  = v[0] + v[1] + v[2] + v[3];
    float s2 = v[0]*v[0] + v[1]*v[1] + v[2]*v[2] + v[3]*v[3];
    for (int off = 1; off < 64; off <<= 1) {
        s  += __shfl_xor(s,  off);
        s2 += __shfl_xor(s2, off);
    }
    const int w = tid >> 6;
    if ((tid & 63) == 0) { red[0][w] = s; red[1][w] = s2; }
    __syncthreads();
    s  = red[0][0] + red[0][1] + red[0][2] + red[0][3];
    s2 = red[1][0] + red[1][1] + red[1][2] + red[1][3];
    const float mu  = s * (1.0f / 1024.0f);
    const float var = s2 * (1.0f / 1024.0f) - mu * mu;
    const float rstd = rsqrtf(var + 1e-5f);
    fvec4 gv = *(const fvec4*)(g + tid * 4);
    fvec4 bv = *(const fvec4*)(bvec + tid * 4);
    u16 o4[4];
    for (int i = 0; i < 4; ++i)
        o4[i] = f2bf((v[i] - mu) * rstd * gv[i] + bv[i]);
    u32 lo = (u32)o4[0] | ((u32)o4[1] << 16);
    u32 hi = (u32)o4[2] | ((u32)o4[3] << 16);
    u32* dst = (u32*)(out + (size_t)row * 1024 + tid * 4);
    dst[0] = lo; dst[1] = hi;
}

// ---------------------------------------------------------------------------
// GEMM, BK=64 single-buffered, XCD-swizzled 1-D grid.
// C[M][N] = A[M][K] @ Bt[N][K]^T, both bf16. TM=128 always (32 M-tiles).
// Swizzle: XCD = id%8 (round-robin dispatch, m09). XCD k owns NYP=GY/8
// consecutive B-panels; sweeps all 32 A-tiles per panel -> B-panel stays
// L2-resident, A-panels absorbed by L3 -> barrier drains hit cache.
// MODE 0: out bf16 = acc
// MODE 1: out fp32 = acc + bias[n] + res[m][n]
// MODE 2: out bf16 = gelu(acc + bias[n])   (exact erf)
// ---------------------------------------------------------------------------
template <int MODE, int WM, int WN, int MT, int NT, int NYP>
__global__ __launch_bounds__(256)
void gemm64(const u16* __restrict__ A, const u16* __restrict__ Bt,
            const float* __restrict__ bias, const float* __restrict__ res,
            void* __restrict__ out, int M, int N, int K) {
    constexpr int TM = WM * MT * 16;
    constexpr int TN = WN * NT * 16;
    constexpr int AJ = TM / 64;
    constexpr int BJ = TN / 64;
    static_assert(TM == 128, "swizzle assumes 32 M-tiles");
    __shared__ __attribute__((aligned(16))) u16 sA[2 * TM * 32];  // [kt][row][32]
    __shared__ __attribute__((aligned(16))) u16 sB[2 * TN * 32];
    const int id = blockIdx.x;
    const int j  = id >> 3;
    const int by = (id & 7) * NYP + (j >> 5);
    const int bx = j & 31;
    const int tid = threadIdx.x;
    const int lane = tid & 63, w = tid >> 6;
    const int wm = w / WN, wn = w % WN;
    const int q = lane >> 4, l16 = lane & 15;

    f32x4 acc[MT][NT];
#pragma unroll
    for (int i = 0; i < MT; ++i)
#pragma unroll
        for (int jj = 0; jj < NT; ++jj) acc[i][jj] = (f32x4)0.0f;

    const int sr = lane >> 2;            // 0..15
    const int kc = (lane & 3) * 8;       // 0,8,16,24
    const u16* gA[AJ];
    const u16* gB[BJ];
#pragma unroll
    for (int jj = 0; jj < AJ; ++jj)
        gA[jj] = A + (size_t)(bx * TM + (jj * 4 + w) * 16 + sr) * K + kc;
#pragma unroll
    for (int jj = 0; jj < BJ; ++jj)
        gB[jj] = Bt + (size_t)(by * TN + (jj * 4 + w) * 16 + sr) * K + kc;

    for (int k0 = 0; k0 < K; k0 += 64) {
#pragma unroll
        for (int kt = 0; kt < 2; ++kt) {
#pragma unroll
            for (int jj = 0; jj < AJ; ++jj)
                gload16(gA[jj] + k0 + kt * 32, &sA[kt * TM * 32 + (jj * 4 + w) * 512]);
#pragma unroll
            for (int jj = 0; jj < BJ; ++jj)
                gload16(gB[jj] + k0 + kt * 32, &sB[kt * TN * 32 + (jj * 4 + w) * 512]);
        }
        __syncthreads();
#pragma unroll
        for (int kt = 0; kt < 2; ++kt) {
            bf16x8 af[MT], bf[NT];
#pragma unroll
            for (int mt = 0; mt < MT; ++mt)
                af[mt] = *(const bf16x8*)&sA[kt * TM * 32 +
                         (wm * MT * 16 + mt * 16 + l16) * 32 + q * 8];
#pragma unroll
            for (int nt = 0; nt < NT; ++nt)
                bf[nt] = *(const bf16x8*)&sB[kt * TN * 32 +
                         (wn * NT * 16 + nt * 16 + l16) * 32 + q * 8];
#pragma unroll
            for (int mt = 0; mt < MT; ++mt)
#pragma unroll
                for (int nt = 0; nt < NT; ++nt)
                    acc[mt][nt] = mfma16(af[mt], bf[nt], acc[mt][nt]);
        }
        __syncthreads();
    }

#pragma unroll
    for (int mt = 0; mt < MT; ++mt)
#pragma unroll
        for (int nt = 0; nt < NT; ++nt)
#pragma unroll
            for (int r = 0; r < 4; ++r) {
                const int row = bx * TM + wm * MT * 16 + mt * 16 + q * 4 + r;
                const int col = by * TN + wn * NT * 16 + nt * 16 + l16;
                const size_t idx = (size_t)row * N + col;
                float v = acc[mt][nt][r];
                if (MODE == 0) {
                    ((u16*)out)[idx] = f2bf(v);
                } else if (MODE == 1) {
                    ((float*)out)[idx] = v + bias[col] + res[idx];
                } else {
                    float t = v + bias[col];
                    ((u16*)out)[idx] = f2bf(t * 0.5f * (1.0f + erff(t * 0.70710678118f)));
                }
            }
}

// ---------------------------------------------------------------------------
// Flash attention v3 (unchanged from round 3).
// ---------------------------------------------------------------------------
__global__ __launch_bounds__(256)
void attention3(const u16* __restrict__ qkv, const u16* __restrict__ vT,
                u16* __restrict__ o) {
    __shared__ __attribute__((aligned(16))) u16 sK[64][72];   // [key][d]
    __shared__ __attribute__((aligned(16))) u16 sV[64][72];   // [d][key]

    const int tid = threadIdx.x;
    const int lane = tid & 63, w = tid >> 6;
    const int qc = lane >> 4, l16 = lane & 15;
    const int bx = blockIdx.x;
    const int qt = bx & 15, h = (bx >> 4) & 15, b = bx >> 8;
    const int rowbase = qt * 128 + w * 32;

    bf16x8 aQ[2][2];
#pragma unroll
    for (int mtq = 0; mtq < 2; ++mtq)
#pragma unroll
        for (int kd = 0; kd < 2; ++kd)
            aQ[mtq][kd] = *(const bf16x8*)(qkv +
                (size_t)(b * 2048 + rowbase + mtq * 16 + l16) * 3072 +
                h * 64 + kd * 32 + qc * 8);

    f32x4 accO[2][4];
#pragma unroll
    for (int mtq = 0; mtq < 2; ++mtq)
#pragma unroll
        for (int dt = 0; dt < 4; ++dt) accO[mtq][dt] = (f32x4)0.0f;
    float lsum[2] = {0.0f, 0.0f};

    const int srr = tid >> 3;            // 0..31
    const int sc8 = (tid & 7) * 8;       // 0..56
    const u16* gK = qkv + (size_t)(b * 2048 + srr) * 3072 + 1024 + h * 64 + sc8;
    const u16* gV = vT + (size_t)(h * 64 + srr) * 4096 + b * 2048 + sc8;

    i32x4 cK[2], cV[2];
    cK[0] = *(const i32x4*)gK;
    cK[1] = *(const i32x4*)(gK + (size_t)32 * 3072);
    cV[0] = *(const i32x4*)gV;
    cV[1] = *(const i32x4*)(gV + (size_t)32 * 4096);

    const int sig_base = ((l16 >> 2) << 3) + (l16 & 3);   // q*8 + r

    for (int kc = 0; kc < 32; ++kc) {
        __syncthreads();
        *(i32x4*)&sK[srr][sc8]      = cK[0];
        *(i32x4*)&sK[srr + 32][sc8] = cK[1];
        *(i32x4*)&sV[srr][sc8]      = cV[0];
        *(i32x4*)&sV[srr + 32][sc8] = cV[1];
        const int kn = (kc + 1 < 32) ? kc + 1 : 31;
        i32x4 nK[2], nV[2];
        nK[0] = *(const i32x4*)(gK + (size_t)kn * 64 * 3072);
        nK[1] = *(const i32x4*)(gK + ((size_t)kn * 64 + 32) * 3072);
        nV[0] = *(const i32x4*)(gV + kn * 64);
        nV[1] = *(const i32x4*)(gV + (size_t)32 * 4096 + kn * 64);
        __syncthreads();

        bf16x8 kf[4][2];
#pragma unroll
        for (int mk = 0; mk < 4; ++mk) {
            const int krow = ((mk & 1) << 5) + ((mk >> 1) << 2) + sig_base;
            kf[mk][0] = *(const bf16x8*)&sK[krow][qc * 8];
            kf[mk][1] = *(const bf16x8*)&sK[krow][32 + qc * 8];
        }

        f32x4 s[2][4];
#pragma unroll
        for (int mtq = 0; mtq < 2; ++mtq)
#pragma unroll
            for (int mk = 0; mk < 4; ++mk) {
                f32x4 z = (f32x4)0.0f;
                z = mfma16(kf[mk][0], aQ[mtq][0], z);
                z = mfma16(kf[mk][1], aQ[mtq][1], z);
                s[mtq][mk] = z;
            }

        bf16x8 pf[2][2];
#pragma unroll
        for (int mtq = 0; mtq < 2; ++mtq) {
            float ls = 0.0f;
#pragma unroll
            for (int mk = 0; mk < 4; ++mk)
#pragma unroll
                for (int r = 0; r < 4; ++r) {
                    float p = __expf(s[mtq][mk][r] * 0.125f);
                    s[mtq][mk][r] = p;
                    ls += p;
                }
            lsum[mtq] += ls;
#pragma unroll
            for (int kt = 0; kt < 2; ++kt)
#pragma unroll
                for (int jj = 0; jj < 4; ++jj) {
                    pf[mtq][kt][jj]     = (short)f2bf(s[mtq][kt][jj]);
                    pf[mtq][kt][4 + jj] = (short)f2bf(s[mtq][2 + kt][jj]);
                }
        }

#pragma unroll
        for (int kt = 0; kt < 2; ++kt)
#pragma unroll
            for (int dt = 0; dt < 4; ++dt) {
                bf16x8 vf = *(const bf16x8*)&sV[dt * 16 + l16][kt * 32 + qc * 8];
#pragma unroll
                for (int mtq = 0; mtq < 2; ++mtq)
                    accO[mtq][dt] = mfma16(pf[mtq][kt], vf, accO[mtq][dt]);
            }

        cK[0] = nK[0]; cK[1] = nK[1];
        cV[0] = nV[0]; cV[1] = nV[1];
    }

#pragma unroll
    for (int mtq = 0; mtq < 2; ++mtq) {
        lsum[mtq] += __shfl_xor(lsum[mtq], 16);
        lsum[mtq] += __shfl_xor(lsum[mtq], 32);
    }

#pragma unroll
    for (int mtq = 0; mtq < 2; ++mtq)
#pragma unroll
        for (int r = 0; r < 4; ++r) {
            const float lr = __shfl(lsum[mtq], qc * 4 + r, 16);
            const float inv = 1.0f / lr;
            const size_t tok = (size_t)b * 2048 + rowbase + mtq * 16 + qc * 4 + r;
#pragma unroll
            for (int dt = 0; dt < 4; ++dt)
                o[tok * 1024 + h * 64 + dt * 16 + l16] = f2bf(accO[mtq][dt][r] * inv);
        }
}

// ---------------------------------------------------------------------------
extern "C" void kernel_launch(void* const* d_in, const int* in_sizes, int n_in,
                              void* d_out, int out_size, void* d_ws, size_t ws_size,
                              hipStream_t stream) {
    const float* x      = (const float*)d_in[0];
    const float* ln1_g  = (const float*)d_in[1];
    const float* ln1_b  = (const float*)d_in[2];
    const float* w_qkv  = (const float*)d_in[3];
    const float* w_proj = (const float*)d_in[4];
    const float* b_proj = (const float*)d_in[5];
    const float* ln2_g  = (const float*)d_in[6];
    const float* ln2_b  = (const float*)d_in[7];
    const float* w_fc1  = (const float*)d_in[8];
    const float* b_fc1  = (const float*)d_in[9];
    const float* w_fc2  = (const float*)d_in[10];
    const float* b_fc2  = (const float*)d_in[11];
    float* out = (float*)d_out;

    // workspace layout (bytes); total ~104 MB
    char* ws = (char*)d_ws;
    u16*   wqkvT  = (u16*)(ws + 0);           //  6 MB  [3072][1024]
    u16*   wprojT = (u16*)(ws + 6291456);     //  2 MB  [1024][1024]
    u16*   wfc1T  = (u16*)(ws + 8388608);     //  8 MB  [4096][1024]
    u16*   wfc2T  = (u16*)(ws + 16777216);    //  8 MB  [1024][4096]
    u16*   hA     = (u16*)(ws + 25165824);    //  8 MB  ln1 out; reused for attn out
    u16*   qkv    = (u16*)(ws + 33554432);    // 24 MB  [4096][3072]; reused for h2
    float* x1     = (float*)(ws + 58720256);  // 16 MB  [4096][1024] fp32
    u16*   gbuf   = (u16*)(ws + 75497472);    // 32 MB  [4096][4096] gelu out
    u16*   vT     = (u16*)(ws + 75497472);    //  8 MB  aliases gbuf (dead before fc1)

    dim3 blk(256);
    transpose_all<<<12288, blk, 0, stream>>>(w_qkv, wqkvT, w_proj, wprojT,
                                             w_fc1, wfc1T, w_fc2, wfc2T);

    ln_kernel<<<4096, blk, 0, stream>>>(x, ln1_g, ln1_b, hA);
    gemm64<0, 2, 2, 4, 4, 3><<<768, blk, 0, stream>>>(hA, wqkvT, nullptr, nullptr, qkv, 4096, 3072, 1024);
    vtrans<<<dim3(64, 16), blk, 0, stream>>>(qkv, vT);
    attention3<<<512, blk, 0, stream>>>(qkv, vT, hA);
    gemm64<1, 4, 1, 2, 4, 2><<<512, blk, 0, stream>>>(hA, wprojT, b_proj, x, x1, 4096, 1024, 1024);

    u16* h2 = qkv;  // qkv dead after attention
    ln_kernel<<<4096, blk, 0, stream>>>(x1, ln2_g, ln2_b, h2);
    gemm64<2, 2, 2, 4, 4, 4><<<1024, blk, 0, stream>>>(h2, wfc1T, b_fc1, nullptr, gbuf, 4096, 4096, 1024);
    gemm64<1, 4, 1, 2, 4, 2><<<512, blk, 0, stream>>>(gbuf, wfc2T, b_fc2, x1, out, 4096, 1024, 4096);
}